// Round 5
// baseline (53.382 us; speedup 1.0000x reference)
//
#include <hip/hip_runtime.h>
#include <math.h>

#define HID 1024
#define NBLK 1024   // == SEQ_LEN/32 == HID
#define RLX __ATOMIC_RELAXED
#define AGT __HIP_MEMORY_SCOPE_AGENT

// Barrier/control state lives in a device global: the harness poisons only
// d_out/d_ws, never module globals. Zero at load; self-reset at kernel end ->
// every call starts AND ends with all-zero ctl (graph-replay deterministic).
__device__ unsigned g_ctl[2304];

// word offsets (each counter on its own 128B line)
#define SUBA(g)  ((g) << 5)
#define MASTERA  1024
#define FLAGA    1056
#define SUBB(g)  (1088 + ((g) << 5))
#define MASTERB  2112
#define FLAGB    2144
#define DEPART   2176

__device__ __forceinline__ unsigned ld32(const unsigned* p) { return __hip_atomic_load(p, RLX, AGT); }
__device__ __forceinline__ void st32(unsigned* p, unsigned v) { __hip_atomic_store(p, v, RLX, AGT); }
__device__ __forceinline__ unsigned long long ld64(const unsigned long long* p) { return __hip_atomic_load(p, RLX, AGT); }
__device__ __forceinline__ void st64(unsigned long long* p, unsigned long long v) { __hip_atomic_store(p, v, RLX, AGT); }
__device__ __forceinline__ unsigned add32(unsigned* p, unsigned v) { return __hip_atomic_fetch_add(p, v, RLX, AGT); }
__device__ __forceinline__ void vfence() { asm volatile("s_waitcnt vmcnt(0)" ::: "memory"); }
__device__ __forceinline__ void spin(unsigned* f) {
    for (int i = 0; i < (1 << 24); ++i) {           // bounded: ~0.5s, then bail (wrong answer > hang)
        if (ld32(f)) return;
        __builtin_amdgcn_s_sleep(2);
    }
}
__device__ __forceinline__ void mzmerge(float& m, float& z, float m2, float z2) {
    const float M = fmaxf(m, m2);
    z = z * __expf(m - M) + z2 * __expf(m2 - M);
    m = M;
}

__global__ void __launch_bounds__(256, 4)            // VGPR<=128 -> >=4 blk/CU -> 1024 co-resident
k_all(const float* __restrict__ W, const float* __restrict__ hvec,
      const float* __restrict__ enc, unsigned* __restrict__ vglob,
      unsigned long long* __restrict__ bstats,
      unsigned long long* __restrict__ gstat,
      unsigned long long* __restrict__ fstat,
      float* __restrict__ out) {
    const int t = threadIdx.x, bid = blockIdx.x;
    const int wave = t >> 6, lane = t & 63;
    const int grp = bid >> 5;
    unsigned* ctl = g_ctl;

    __shared__ float red[4];
    __shared__ float v_lds[HID];
    __shared__ float wm[4], wz[4];
    __shared__ float e_lds[32];
    __shared__ float2 smz;

    // ---- Phase 1: v[bid] = sum_d hvec[d] * W[d*H + bid] -------------------
    {
        float acc = 0.f;
#pragma unroll
        for (int i = 0; i < 4; ++i) {
            const int d = (i << 8) + t;
            acc = fmaf(hvec[d], W[d * HID + bid], acc);
        }
#pragma unroll
        for (int off = 32; off; off >>= 1) acc += __shfl_xor(acc, off, 64);
        if (!lane) red[wave] = acc;
        __syncthreads();
        if (!t) {
            st32(vglob + bid, __float_as_uint((red[0] + red[1]) + (red[2] + red[3])));
            vfence();                                 // v at MALL before arrival RMW
            if (add32(ctl + SUBA(grp), 1u) == 31u)
                if (add32(ctl + MASTERA, 1u) == 31u) st32(ctl + FLAGA, 1u);
            spin(ctl + FLAGA);
        }
        __syncthreads();
    }

    // ---- v -> LDS (relaxed agent loads bypass possibly-stale L2) ----------
#pragma unroll
    for (int i = 0; i < 4; ++i) {
        const int idx = (i << 8) + t;
        v_lds[idx] = __uint_as_float(ld32(vglob + idx));
    }
    __syncthreads();

    // ---- Phase 2: energies for rows [bid*32, bid*32+32) -------------------
    {
        const int row0 = (bid << 5) + (wave << 3);
        const float4 vr0 = *reinterpret_cast<const float4*>(v_lds +       (lane << 2));
        const float4 vr1 = *reinterpret_cast<const float4*>(v_lds + 256 + (lane << 2));
        const float4 vr2 = *reinterpret_cast<const float4*>(v_lds + 512 + (lane << 2));
        const float4 vr3 = *reinterpret_cast<const float4*>(v_lds + 768 + (lane << 2));

        float m = -__builtin_inff();
        float z = 0.f;

        const float4* p = reinterpret_cast<const float4*>(enc + (size_t)row0 * HID) + lane;
        float4 a = p[0], b = p[64], c = p[128], d = p[192];

#pragma unroll
        for (int r = 0; r < 8; ++r) {
            float4 na, nb, nc, nd;
            if (r < 7) {
                const float4* q = p + (size_t)(r + 1) * 256;
                na = q[0]; nb = q[64]; nc = q[128]; nd = q[192];
            }
            float acc = a.x * vr0.x + a.y * vr0.y + a.z * vr0.z + a.w * vr0.w
                      + b.x * vr1.x + b.y * vr1.y + b.z * vr1.z + b.w * vr1.w
                      + c.x * vr2.x + c.y * vr2.y + c.z * vr2.z + c.w * vr2.w
                      + d.x * vr3.x + d.y * vr3.y + d.z * vr3.z + d.w * vr3.w;
#pragma unroll
            for (int off = 32; off; off >>= 1) acc += __shfl_xor(acc, off, 64);
            if (!lane) e_lds[(wave << 3) + r] = acc;
            mzmerge(m, z, acc, 1.f);                 // z += exp(acc - m) with rescale
            a = na; b = nb; c = nc; d = nd;
        }
        if (!lane) { wm[wave] = m; wz[wave] = z; }
    }
    __syncthreads();

    // ---- publish bstat; barrier B with arrival-coupled hierarchical reduce -
    if (!t) {
        float M = wm[0], Z = wz[0];
        mzmerge(M, Z, wm[1], wz[1]);
        mzmerge(M, Z, wm[2], wz[2]);
        mzmerge(M, Z, wm[3], wz[3]);
        st64(bstats + bid, __builtin_bit_cast(unsigned long long, make_float2(M, Z)));
        vfence();
        if (add32(ctl + SUBB(grp), 1u) == 31u) {
            // group leader: reduce my group's 32 bstats (4 chunks x 8 MLP loads)
            float gm = -__builtin_inff(), gz = 0.f;
            const unsigned long long* B = bstats + (grp << 5);
#pragma unroll
            for (int c = 0; c < 4; ++c) {
                unsigned long long bb[8];
#pragma unroll
                for (int i = 0; i < 8; ++i) bb[i] = ld64(B + (c << 3) + i);
#pragma unroll
                for (int i = 0; i < 8; ++i) {
                    const float2 s = __builtin_bit_cast(float2, bb[i]);
                    mzmerge(gm, gz, s.x, s.y);
                }
            }
            st64(gstat + grp, __builtin_bit_cast(unsigned long long, make_float2(gm, gz)));
            vfence();
            if (add32(ctl + MASTERB, 1u) == 31u) {
                float fm = -__builtin_inff(), fz = 0.f;
#pragma unroll
                for (int c = 0; c < 4; ++c) {
                    unsigned long long bb[8];
#pragma unroll
                    for (int i = 0; i < 8; ++i) bb[i] = ld64(gstat + (c << 3) + i);
#pragma unroll
                    for (int i = 0; i < 8; ++i) {
                        const float2 s = __builtin_bit_cast(float2, bb[i]);
                        mzmerge(fm, fz, s.x, s.y);
                    }
                }
                st64(fstat, __builtin_bit_cast(unsigned long long, make_float2(fm, fz)));
                vfence();
                st32(ctl + FLAGB, 1u);
            }
        }
        spin(ctl + FLAGB);
        smz = __builtin_bit_cast(float2, ld64(fstat));
    }
    __syncthreads();

    // ---- Phase 3: write this block's 32 outputs ---------------------------
    if (t < 32) out[(bid << 5) + t] = __expf(e_lds[t] - smz.x) * (1.f / smz.y);

    // ---- self-reset: last departing block zeroes ctl for the next replay --
    if (!t) {
        if (add32(ctl + DEPART, 1u) == (NBLK - 1)) {
#pragma unroll
            for (int g = 0; g < 32; ++g) { st32(ctl + SUBA(g), 0u); st32(ctl + SUBB(g), 0u); }
            st32(ctl + MASTERA, 0u); st32(ctl + FLAGA, 0u);
            st32(ctl + MASTERB, 0u); st32(ctl + FLAGB, 0u);
            st32(ctl + DEPART, 0u);
        }
    }
}

extern "C" void kernel_launch(void* const* d_in, const int* in_sizes, int n_in,
                              void* d_out, int out_size, void* d_ws, size_t ws_size,
                              hipStream_t stream) {
    const float* hidden = (const float*)d_in[0];   // [1,1,1024]
    const float* enc    = (const float*)d_in[1];   // [32768,1024]
    const float* W      = (const float*)d_in[2];   // [1024,1024]
    // d_in[3] (bias) cancels in softmax (constant shift) — never read.

    float* ws = (float*)d_ws;
    unsigned* vglob = (unsigned*)ws;                                  // 1024 u32
    unsigned long long* bstats = (unsigned long long*)(ws + HID);     // 1024 u64 (8B-aligned)
    unsigned long long* gstat  = bstats + 1024;                       // 32 u64
    unsigned long long* fstat  = gstat + 32;                          // 1 u64

    k_all<<<NBLK, 256, 0, stream>>>(W, hidden, enc, vglob, bstats, gstat, fstat,
                                    (float*)d_out);
}

// Round 6
// 38.788 us; speedup vs baseline: 1.3762x; 1.3762x over previous
//
#include <hip/hip_runtime.h>
#include <math.h>

#define HID 1024
#define NBLK 1024   // == SEQ_LEN/32 == HID
#define RLX __ATOMIC_RELAXED
#define AGT __HIP_MEMORY_SCOPE_AGENT

// Barrier/control state in a device global (harness poisons only d_out/d_ws).
// Zero-initialized at module load; self-reset at end of every call.
__device__ unsigned g_ctl[1152];
// word offsets, each counter on its own 128B line:
#define SUB(g)   ((g) << 5)     // 32 group arrival counters
#define MASTER   1024
#define FLAG     1056
#define DEPART   1088

__device__ __forceinline__ unsigned ld32(const unsigned* p) { return __hip_atomic_load(p, RLX, AGT); }
__device__ __forceinline__ void st32(unsigned* p, unsigned v) { __hip_atomic_store(p, v, RLX, AGT); }
__device__ __forceinline__ unsigned long long ld64(const unsigned long long* p) { return __hip_atomic_load(p, RLX, AGT); }
__device__ __forceinline__ void st64(unsigned long long* p, unsigned long long v) { __hip_atomic_store(p, v, RLX, AGT); }
__device__ __forceinline__ unsigned add32(unsigned* p, unsigned v) { return __hip_atomic_fetch_add(p, v, RLX, AGT); }
__device__ __forceinline__ void vfence() { asm volatile("s_waitcnt vmcnt(0)" ::: "memory"); }
__device__ __forceinline__ void spin(unsigned* f) {
    for (int i = 0; i < (1 << 24); ++i) {          // bounded: fail -> wrong answer, not hang
        if (ld32(f)) return;
        __builtin_amdgcn_s_sleep(2);
    }
}
__device__ __forceinline__ void mzmerge(float& m, float& z, float m2, float z2) {
    const float M = fmaxf(m, m2);
    z = z * __expf(m - M) + z2 * __expf(m2 - M);
    m = M;
}

// ---------------------------------------------------------------------------
// K1: v = W^T h. One block per column; consumers see v via the kernel
// boundary (no manual coherence). Proven in R2.
// ---------------------------------------------------------------------------
__global__ void __launch_bounds__(256) k_matvec(const float* __restrict__ W,
                                                const float* __restrict__ hvec,
                                                float* __restrict__ v) {
    const int col = blockIdx.x;
    const int t = threadIdx.x;
    float acc = 0.f;
#pragma unroll
    for (int i = 0; i < 4; ++i) {
        const int d = (i << 8) + t;
        acc = fmaf(hvec[d], W[d * HID + col], acc);
    }
#pragma unroll
    for (int off = 32; off; off >>= 1) acc += __shfl_xor(acc, off, 64);
    __shared__ float red[4];
    if ((t & 63) == 0) red[t >> 6] = acc;
    __syncthreads();
    if (t == 0) v[col] = (red[0] + red[1]) + (red[2] + red[3]);
}

// ---------------------------------------------------------------------------
// K2: energies + leader-tail finalize. No full-grid barrier:
//  - every block publishes its 32 energies + (m,z) via relaxed agent stores,
//    vmcnt-fences, then arrives on its group counter (32 RMWs/line).
//  - last arriver of each group -> master counter -> becomes tail block with
//    slice id om (0..31). om==31 (global last) reduces 1024 bstats, publishes
//    (M,Z), sets flag; the other 31 leaders poll it (31 pollers, no thrash).
//  - each tail block writes 1024 outputs; departure counter self-resets ctl.
// 992 blocks exit immediately -> no co-residency requirement, no deadlock.
// ---------------------------------------------------------------------------
__global__ void __launch_bounds__(256)
k_energy(const float* __restrict__ enc, const float* __restrict__ v,
         unsigned* __restrict__ eglob, unsigned long long* __restrict__ bstats,
         unsigned long long* __restrict__ fstat, float* __restrict__ out) {
    const int t = threadIdx.x, bid = blockIdx.x;
    const int wave = t >> 6, lane = t & 63;

    __shared__ float wm[4], wz[4];
    __shared__ float e_lds[32];
    __shared__ float sm[256], sz[256];
    __shared__ int s_role;
    __shared__ float2 s_mz;

    // ---- energies for rows [bid*32, bid*32+32) ----------------------------
    {
        const int row0 = (bid << 5) + (wave << 3);
        const float4 vr0 = *reinterpret_cast<const float4*>(v +       (lane << 2));
        const float4 vr1 = *reinterpret_cast<const float4*>(v + 256 + (lane << 2));
        const float4 vr2 = *reinterpret_cast<const float4*>(v + 512 + (lane << 2));
        const float4 vr3 = *reinterpret_cast<const float4*>(v + 768 + (lane << 2));

        float m = -__builtin_inff();
        float z = 0.f;

        const float4* p = reinterpret_cast<const float4*>(enc + (size_t)row0 * HID) + lane;
        float4 a = p[0], b = p[64], c = p[128], d = p[192];

#pragma unroll
        for (int r = 0; r < 8; ++r) {
            float4 na, nb, nc, nd;
            if (r < 7) {
                const float4* q = p + (size_t)(r + 1) * 256;
                na = q[0]; nb = q[64]; nc = q[128]; nd = q[192];
            }
            float acc = a.x * vr0.x + a.y * vr0.y + a.z * vr0.z + a.w * vr0.w
                      + b.x * vr1.x + b.y * vr1.y + b.z * vr1.z + b.w * vr1.w
                      + c.x * vr2.x + c.y * vr2.y + c.z * vr2.z + c.w * vr2.w
                      + d.x * vr3.x + d.y * vr3.y + d.z * vr3.z + d.w * vr3.w;
#pragma unroll
            for (int off = 32; off; off >>= 1) acc += __shfl_xor(acc, off, 64);
            if (!lane) e_lds[(wave << 3) + r] = acc;
            mzmerge(m, z, acc, 1.f);
            a = na; b = nb; c = nc; d = nd;
        }
        if (!lane) { wm[wave] = m; wz[wave] = z; }
    }
    __syncthreads();

    // ---- publish (wave 0), arrive ----------------------------------------
    if (t < 32) st32(eglob + (bid << 5) + t, __float_as_uint(e_lds[t]));
    if (t == 0) {
        float M = wm[0], Z = wz[0];
        mzmerge(M, Z, wm[1], wz[1]);
        mzmerge(M, Z, wm[2], wz[2]);
        mzmerge(M, Z, wm[3], wz[3]);
        st64(bstats + bid, __builtin_bit_cast(unsigned long long, make_float2(M, Z)));
        vfence();                                   // publications at MALL before arrival
        int role = -1;
        if (add32(g_ctl + SUB(bid >> 5), 1u) == 31u)
            role = (int)add32(g_ctl + MASTER, 1u);  // 0..31; 31 == global last
        s_role = role;
    }
    __syncthreads();
    const int role = s_role;
    if (role < 0) return;                           // 992 blocks done

    // ---- tail: 32 leader blocks ------------------------------------------
    if (role == 31) {
        // global last: all 1024 bstats are at the MALL -> block-wide reduce
        float m = -__builtin_inff(), z = 0.f;
#pragma unroll
        for (int i = 0; i < 4; ++i) {
            const unsigned long long bits = ld64(bstats + t + (i << 8));
            const float2 s = __builtin_bit_cast(float2, bits);
            mzmerge(m, z, s.x, s.y);
        }
        sm[t] = m; sz[t] = z;
        __syncthreads();
        for (int off = 128; off; off >>= 1) {
            if (t < off) {
                float m1 = sm[t], z1 = sz[t];
                mzmerge(m1, z1, sm[t + off], sz[t + off]);
                sm[t] = m1; sz[t] = z1;
            }
            __syncthreads();
        }
        if (t == 0) {
            st64(fstat, __builtin_bit_cast(unsigned long long, make_float2(sm[0], sz[0])));
            vfence();
            st32(g_ctl + FLAG, 1u);
        }
    } else {
        if (t == 0) spin(g_ctl + FLAG);             // <=31 pollers on this line
    }
    __syncthreads();
    if (t == 0) s_mz = __builtin_bit_cast(float2, ld64(fstat));
    __syncthreads();

    const float M = s_mz.x;
    const float rZ = 1.f / s_mz.y;
    const int base = role << 10;                    // 1024 outputs per leader
#pragma unroll
    for (int i = 0; i < 4; ++i) {
        const int r = base + (i << 8) + t;
        const float e = __uint_as_float(ld32(eglob + r));
        out[r] = __expf(e - M) * rZ;
    }

    // ---- self-reset (last departing leader) ------------------------------
    if (t == 0) {
        if (add32(g_ctl + DEPART, 1u) == 31u) {
#pragma unroll
            for (int g = 0; g < 32; ++g) st32(g_ctl + SUB(g), 0u);
            st32(g_ctl + MASTER, 0u);
            st32(g_ctl + FLAG, 0u);
            st32(g_ctl + DEPART, 0u);
        }
    }
}

extern "C" void kernel_launch(void* const* d_in, const int* in_sizes, int n_in,
                              void* d_out, int out_size, void* d_ws, size_t ws_size,
                              hipStream_t stream) {
    const float* hidden = (const float*)d_in[0];   // [1,1,1024]
    const float* enc    = (const float*)d_in[1];   // [32768,1024]
    const float* W      = (const float*)d_in[2];   // [1024,1024]
    // d_in[3] (bias) cancels in softmax (constant shift) — never read.

    float* ws = (float*)d_ws;
    float* v        = ws;                                         // 1024 f32
    unsigned* eglob = (unsigned*)(ws + HID);                      // 32768 u32
    unsigned long long* bstats = (unsigned long long*)(ws + HID + 32768); // 1024 u64 (8B aligned)
    unsigned long long* fstat  = bstats + 1024;                   // 1 u64

    k_matvec<<<HID, 256, 0, stream>>>(W, hidden, v);
    k_energy<<<NBLK, 256, 0, stream>>>(enc, v, eglob, bstats, fstat, (float*)d_out);
}

// Round 7
// 36.891 us; speedup vs baseline: 1.4470x; 1.0514x over previous
//
#include <hip/hip_runtime.h>
#include <hip/hip_bf16.h>
#include <math.h>

#define SEQ_LEN 32768
#define HID 1024
#define NBLK_E 2048          // energy blocks: 16 rows each
#define SWZ 997              // odd -> (bid*SWZ)&2047 is a bijection on [0,2048)

// ---------------------------------------------------------------------------
// K1: v = W^T h. One block per column (known-good from R2; W is L2/L3-hot,
// cost ~1 us regardless of layout).
// ---------------------------------------------------------------------------
__global__ void __launch_bounds__(256) k_matvec(const float* __restrict__ W,
                                                const float* __restrict__ hvec,
                                                float* __restrict__ v) {
    const int col = blockIdx.x;
    const int t = threadIdx.x;
    float acc = 0.f;
#pragma unroll
    for (int i = 0; i < 4; ++i) {
        const int d = (i << 8) + t;
        acc = fmaf(hvec[d], W[d * HID + col], acc);
    }
#pragma unroll
    for (int off = 32; off; off >>= 1) acc += __shfl_xor(acc, off, 64);
    __shared__ float red[4];
    if ((t & 63) == 0) red[t >> 6] = acc;
    __syncthreads();
    if (t == 0) v[col] = (red[0] + red[1]) + (red[2] + red[3]);
}

// ---------------------------------------------------------------------------
// K2: energies[s] = enc[s,:] . v  — the 128 MB read.
// 2048 blocks x 256 threads (8 blocks/CU, 100% occupancy). Block bid owns
// 16-row chunk ((bid*997)&2047): bijective swizzle so concurrently-running
// blocks are ~62 MB apart -> uniform HBM-channel/MALL-slice load at every
// instant (kills power-of-2 start-address aliasing).
// Each wave: 4 rows, 4x float4 per row per lane, 2-deep row pipeline.
// ---------------------------------------------------------------------------
__global__ void __launch_bounds__(256) k_energy(const float* __restrict__ enc,
                                                const float* __restrict__ v,
                                                float* __restrict__ energies,
                                                float2* __restrict__ bstats) {
    const int t = threadIdx.x;
    const int wave = t >> 6;
    const int lane = t & 63;
    const int chunk = (blockIdx.x * SWZ) & (NBLK_E - 1);
    const int row0 = (chunk << 4) + (wave << 2);

    const float4 vr0 = *reinterpret_cast<const float4*>(v +       (lane << 2));
    const float4 vr1 = *reinterpret_cast<const float4*>(v + 256 + (lane << 2));
    const float4 vr2 = *reinterpret_cast<const float4*>(v + 512 + (lane << 2));
    const float4 vr3 = *reinterpret_cast<const float4*>(v + 768 + (lane << 2));

    float m = -__builtin_inff();
    float z = 0.f;

    const float4* p = reinterpret_cast<const float4*>(enc + (size_t)row0 * HID) + lane;
    float4 a = p[0], b = p[64], c = p[128], d = p[192];

    __shared__ float e_lds[16];

#pragma unroll
    for (int r = 0; r < 4; ++r) {
        float4 na, nb, nc, nd;
        if (r < 3) {
            const float4* q = p + (size_t)(r + 1) * 256;
            na = q[0]; nb = q[64]; nc = q[128]; nd = q[192];
        }
        float acc = a.x * vr0.x + a.y * vr0.y + a.z * vr0.z + a.w * vr0.w
                  + b.x * vr1.x + b.y * vr1.y + b.z * vr1.z + b.w * vr1.w
                  + c.x * vr2.x + c.y * vr2.y + c.z * vr2.z + c.w * vr2.w
                  + d.x * vr3.x + d.y * vr3.y + d.z * vr3.z + d.w * vr3.w;
#pragma unroll
        for (int off = 32; off; off >>= 1) acc += __shfl_xor(acc, off, 64);
        if (lane == 0) {
            energies[row0 + r] = acc;
            e_lds[(wave << 2) + r] = acc;
        }
        const float nm = fmaxf(m, acc);
        z = z * __expf(m - nm) + __expf(acc - nm);
        m = nm;
        a = na; b = nb; c = nc; d = nd;
    }

    __shared__ float wm[4], wz[4];
    if (lane == 0) { wm[wave] = m; wz[wave] = z; }
    __syncthreads();
    if (t == 0) {
        float M = fmaxf(fmaxf(wm[0], wm[1]), fmaxf(wm[2], wm[3]));
        float Z = wz[0] * __expf(wm[0] - M) + wz[1] * __expf(wm[1] - M)
                + wz[2] * __expf(wm[2] - M) + wz[3] * __expf(wm[3] - M);
        bstats[chunk] = make_float2(M, Z);
    }
}

// ---------------------------------------------------------------------------
// K3: reduce 2048 block stats -> (M,Z) redundantly per block (16 KB, L2-hot),
// then write attn[i] = exp(e[i]-M)/Z. 64 blocks x 256 threads.
// ---------------------------------------------------------------------------
__global__ void __launch_bounds__(256) k_final(const float* __restrict__ energies,
                                               const float2* __restrict__ bstats,
                                               float* __restrict__ out) {
    __shared__ float sm[256], sz[256];
    const int t = threadIdx.x;
    float m = -__builtin_inff();
    float z = 0.f;
#pragma unroll
    for (int i = 0; i < 8; ++i) {
        const float2 s = bstats[t + (i << 8)];
        const float nm = fmaxf(m, s.x);
        z = z * __expf(m - nm) + s.y * __expf(s.x - nm);
        m = nm;
    }
    sm[t] = m; sz[t] = z;
    __syncthreads();
    for (int off = 128; off; off >>= 1) {
        if (t < off) {
            const float m1 = sm[t], z1 = sz[t];
            const float m2 = sm[t + off], z2 = sz[t + off];
            const float M = fmaxf(m1, m2);
            sm[t] = M;
            sz[t] = z1 * __expf(m1 - M) + z2 * __expf(m2 - M);
        }
        __syncthreads();
    }
    const float M = sm[0];
    const float rZ = 1.f / sz[0];

    const size_t i = ((size_t)blockIdx.x << 9) + ((size_t)t << 1);
    const float2 e = *reinterpret_cast<const float2*>(energies + i);
    float2 o;
    o.x = __expf(e.x - M) * rZ;
    o.y = __expf(e.y - M) * rZ;
    *reinterpret_cast<float2*>(out + i) = o;
}

extern "C" void kernel_launch(void* const* d_in, const int* in_sizes, int n_in,
                              void* d_out, int out_size, void* d_ws, size_t ws_size,
                              hipStream_t stream) {
    const float* hidden = (const float*)d_in[0];   // [1,1,1024]
    const float* enc    = (const float*)d_in[1];   // [32768,1024]
    const float* W      = (const float*)d_in[2];   // [1024,1024]
    // d_in[3] (bias) cancels in softmax (constant shift) — never read.

    float* ws       = (float*)d_ws;
    float* v        = ws;                            // 1024 floats
    float* energies = ws + HID;                      // 32768 floats
    float2* bstats  = (float2*)(ws + HID + SEQ_LEN); // 2048 float2

    k_matvec<<<HID, 256, 0, stream>>>(W, hidden, v);
    k_energy<<<NBLK_E, 256, 0, stream>>>(enc, v, energies, bstats);
    k_final<<<SEQ_LEN / 512, 256, 0, stream>>>(energies, bstats, (float*)d_out);
}